// Round 4
// baseline (108.170 us; speedup 1.0000x reference)
//
#include <hip/hip_runtime.h>
#include <hip/hip_bf16.h>

#define H 500
#define D_IN 512
#define D_OUT 100
#define STEPS 49

typedef _Float16 h2_t __attribute__((ext_vector_type(2)));

#if defined(__has_builtin)
#if __has_builtin(__builtin_amdgcn_fdot2)
#define HAVE_FDOT2 1
#endif
#endif

__device__ __forceinline__ float fdot2f(h2_t a, h2_t b, float c) {
#ifdef HAVE_FDOT2
    return __builtin_amdgcn_fdot2(a, b, c, false);
#else
    return c + (float)a[0] * (float)b[0] + (float)a[1] * (float)b[1];
#endif
}
__device__ __forceinline__ h2_t bch2(unsigned u) { return __builtin_bit_cast(h2_t, u); }

__device__ __forceinline__ float tanh_fast(float x) {
    // tanh(x) = 1 - 2/(exp(2x)+1); exact at saturation, ~ulp-level mid-range
    const float e = __expf(2.f * x);
    return 1.f - 2.f / (e + 1.f);
}

// Pin a value as an opaque asm result: the register allocator cannot
// rematerialize it from its defining (invariant) load -> stays VGPR-resident.
#define PINV(x) asm volatile("" : "+v"(x))

// ---------------- K01 fused: blocks 0..15 pack W_hh -> f16 blobs; blocks 16..140
// compute xproj (4 rows per block, one per wave).
// Pack layout: K2 thread tid=(w,l) owns rows r=l+64k of col-slice [64w,64w+64).
// Slice h2-pairs 0..23 (cols 0..47) -> registers (blobW, 6x uint4);
// pairs 24..27 (cols 48..55) -> LDS plane A; pairs 28..31 (cols 56..63) -> plane B.
__global__ void k01_pack_xproj(const float* __restrict__ W_hh, const float* __restrict__ x,
                               const float* __restrict__ W_ih, const float* __restrict__ b_ih,
                               const float* __restrict__ b_hh,
                               uint4* __restrict__ blobW, uint4* __restrict__ blobTA,
                               uint4* __restrict__ blobTB, float* __restrict__ xproj) {
    if (blockIdx.x < 16) {
        const int T = blockIdx.x * 256 + threadIdx.x;   // 0..4095
        const int k = T >> 9, tid = T & 511;
        const int w = tid >> 6, l = tid & 63;
        const int row = l + 64 * k;
        const int c0 = w * 64;

        _Float16 v[64];
        if (row < H && w < 7) {
            const float4* src = (const float4*)(W_hh + row * H + c0);
#pragma unroll
            for (int q = 0; q < 16; q++) {
                const float4 f = src[q];
                v[4 * q + 0] = (_Float16)f.x; v[4 * q + 1] = (_Float16)f.y;
                v[4 * q + 2] = (_Float16)f.z; v[4 * q + 3] = (_Float16)f.w;
            }
        } else {
#pragma unroll
            for (int i = 0; i < 64; i++) {
                const int c = c0 + i;
                v[i] = (row < H && c < H) ? (_Float16)W_hh[row * H + c] : (_Float16)0.f;
            }
        }
        unsigned up[32];
#pragma unroll
        for (int i = 0; i < 32; i++) {
            h2_t p{v[2 * i], v[2 * i + 1]};
            up[i] = __builtin_bit_cast(unsigned, p);
        }
#pragma unroll
        for (int j4 = 0; j4 < 6; j4++) {
            uint4 u; u.x = up[4*j4]; u.y = up[4*j4+1]; u.z = up[4*j4+2]; u.w = up[4*j4+3];
            blobW[(k * 6 + j4) * 512 + tid] = u;
        }
        { uint4 u; u.x = up[24]; u.y = up[25]; u.z = up[26]; u.w = up[27]; blobTA[k * 512 + tid] = u; }
        { uint4 u; u.x = up[28]; u.y = up[29]; u.z = up[30]; u.w = up[31]; blobTB[k * 512 + tid] = u; }
    } else {
        const int wv = threadIdx.x >> 6, lane = threadIdx.x & 63;
        const int r = (blockIdx.x - 16) * 4 + wv;      // 0..499
        if (r >= H) return;
        float wr[8];
#pragma unroll
        for (int k = 0; k < 8; k++) wr[k] = W_ih[r * D_IN + k * 64 + lane];
        float p[STEPS];
#pragma unroll
        for (int t = 0; t < STEPS; t++) p[t] = 0.f;
#pragma unroll
        for (int k = 0; k < 8; k++) {
            const float* xr = x + (size_t)(k * 64 + lane) * STEPS;
#pragma unroll
            for (int t = 0; t < STEPS; t++) p[t] = fmaf(wr[k], xr[t], p[t]);
        }
#pragma unroll
        for (int t = 0; t < STEPS; t++) {
            float v = p[t];
            v += __shfl_xor(v, 32); v += __shfl_xor(v, 16); v += __shfl_xor(v, 8);
            v += __shfl_xor(v, 4);  v += __shfl_xor(v, 2);  v += __shfl_xor(v, 1);
            p[t] = v;
        }
        if (lane == 0) {
            const float b = b_ih[r] + b_hh[r];
            for (int t = 0; t < STEPS; t++) xproj[t * H + r] = p[t] + b;
        }
    }
}

// ---------------- K2: single-CU scan. 512 thr = 8 waves, launch_bounds(512,2)
// -> 256-VGPR budget, 1 WG/CU. 192 weight VGPRs/thread PINNED via empty asm
// (non-rematerializable); 8 h2-pairs/row in LDS planes. h as f16[512] in LDS.
__global__ void __launch_bounds__(512, 2)
k2_scan(const float* __restrict__ hidden0,
        const uint4* __restrict__ blobW, const uint4* __restrict__ blobTA,
        const uint4* __restrict__ blobTB,
        const float* __restrict__ xproj, float* __restrict__ Hs) {
    __shared__ uint4 WlA[8][512];               // 64KB [w][r] pairs 24..27
    __shared__ uint4 WlB[8][512];               // 64KB [w][r] pairs 28..31
    __shared__ float pbuf[8][512];              // 16KB
    __shared__ __align__(16) _Float16 h16[512]; // 1KB

    const int tid = threadIdx.x, w = tid >> 6, l = tid & 63;

    unsigned wreg[8][24];
#pragma unroll
    for (int k = 0; k < 8; k++) {
#pragma unroll
        for (int j4 = 0; j4 < 6; j4++) {
            const uint4 u = blobW[(k * 6 + j4) * 512 + tid];
            wreg[k][4 * j4 + 0] = u.x; PINV(wreg[k][4 * j4 + 0]);
            wreg[k][4 * j4 + 1] = u.y; PINV(wreg[k][4 * j4 + 1]);
            wreg[k][4 * j4 + 2] = u.z; PINV(wreg[k][4 * j4 + 2]);
            wreg[k][4 * j4 + 3] = u.w; PINV(wreg[k][4 * j4 + 3]);
        }
        WlA[w][l + 64 * k] = blobTA[k * 512 + tid];
        WlB[w][l + 64 * k] = blobTB[k * 512 + tid];
    }
    h16[tid] = (tid < H) ? (_Float16)hidden0[tid] : (_Float16)0.f;
    __syncthreads();

    const int rs = (tid < H) ? tid : 0;
    for (int t = 0; t < STEPS; t++) {
        const float xp = xproj[t * H + rs];

        float a[8] = {0.f, 0.f, 0.f, 0.f, 0.f, 0.f, 0.f, 0.f};
        const uint4* hsl = (const uint4*)(h16 + w * 64);
#pragma unroll
        for (int b = 0; b < 6; b++) {
            const uint4 hb = hsl[b];
            const h2_t hp0 = bch2(hb.x), hp1 = bch2(hb.y),
                       hp2 = bch2(hb.z), hp3 = bch2(hb.w);
#pragma unroll
            for (int k = 0; k < 8; k++) {
                a[k] = fdot2f(bch2(wreg[k][4 * b + 0]), hp0, a[k]);
                a[k] = fdot2f(bch2(wreg[k][4 * b + 1]), hp1, a[k]);
                a[k] = fdot2f(bch2(wreg[k][4 * b + 2]), hp2, a[k]);
                a[k] = fdot2f(bch2(wreg[k][4 * b + 3]), hp3, a[k]);
            }
        }
        const uint4 hb6 = hsl[6];
        const uint4 hb7 = hsl[7];
        const h2_t hpA0 = bch2(hb6.x), hpA1 = bch2(hb6.y),
                   hpA2 = bch2(hb6.z), hpA3 = bch2(hb6.w);
        const h2_t hpB0 = bch2(hb7.x), hpB1 = bch2(hb7.y),
                   hpB2 = bch2(hb7.z), hpB3 = bch2(hb7.w);
#pragma unroll
        for (int k = 0; k < 8; k++) {
            const int r = l + 64 * k;
            const uint4 ta = WlA[w][r];
            const uint4 tb = WlB[w][r];
            a[k] = fdot2f(bch2(ta.x), hpA0, a[k]);
            a[k] = fdot2f(bch2(ta.y), hpA1, a[k]);
            a[k] = fdot2f(bch2(ta.z), hpA2, a[k]);
            a[k] = fdot2f(bch2(ta.w), hpA3, a[k]);
            a[k] = fdot2f(bch2(tb.x), hpB0, a[k]);
            a[k] = fdot2f(bch2(tb.y), hpB1, a[k]);
            a[k] = fdot2f(bch2(tb.z), hpB2, a[k]);
            a[k] = fdot2f(bch2(tb.w), hpB3, a[k]);
        }
#pragma unroll
        for (int k = 0; k < 8; k++) pbuf[w][64 * k + l] = a[k];  // slot = row
        __syncthreads();

        float s = 0.f;
#pragma unroll
        for (int w2 = 0; w2 < 8; w2++) s += pbuf[w2][tid];
        const float hval = tanh_fast(s + xp);
        if (tid < H) Hs[t * 512 + tid] = hval;
        h16[tid] = (tid < H) ? (_Float16)hval : (_Float16)0.f;
        __syncthreads();
    }
}

// ---------------- K3: out[t][o] = tanh(b_out[o] + sum_c Hs[t][c]*W_out[o][c])
__global__ void k3_out(const float* __restrict__ Hs, const float* __restrict__ W_out,
                       const float* __restrict__ b_out, float* __restrict__ out) {
    const int t = blockIdx.x, o = threadIdx.x;
    if (o < D_OUT) {
        const float4* wr = (const float4*)(W_out + o * H);
        const float4* hr = (const float4*)(Hs + t * 512);
        float acc = b_out[o];
#pragma unroll 5
        for (int i = 0; i < 125; i++) {
            const float4 wv = wr[i];
            const float4 hv = hr[i];
            acc = fmaf(wv.x, hv.x, acc);
            acc = fmaf(wv.y, hv.y, acc);
            acc = fmaf(wv.z, hv.z, acc);
            acc = fmaf(wv.w, hv.w, acc);
        }
        out[t * D_OUT + o] = tanh_fast(acc);
    }
}

extern "C" void kernel_launch(void* const* d_in, const int* in_sizes, int n_in,
                              void* d_out, int out_size, void* d_ws, size_t ws_size,
                              hipStream_t stream) {
    const float* x       = (const float*)d_in[0];
    const float* hidden0 = (const float*)d_in[1];
    const float* W_ih    = (const float*)d_in[2];
    const float* W_hh    = (const float*)d_in[3];
    const float* b_ih    = (const float*)d_in[4];
    const float* b_hh    = (const float*)d_in[5];
    const float* W_out   = (const float*)d_in[6];
    const float* b_out   = (const float*)d_in[7];
    float* out = (float*)d_out;

    char* ws = (char*)d_ws;
    uint4* blobW  = (uint4*)(ws);             // 48*512*16 = 393216
    uint4* blobTA = (uint4*)(ws + 393216);    // 8*512*16  =  65536
    uint4* blobTB = (uint4*)(ws + 458752);    // 8*512*16  =  65536
    float* xproj  = (float*)(ws + 524288);    // 49*500*4 -> 98304
    float* Hs     = (float*)(ws);             // 100352 B, aliases blobW (blobW fully
                                              // consumed in K2 preload before first
                                              // Hs write; K01 rewrites every launch)

    k01_pack_xproj<<<141, 256, 0, stream>>>(W_hh, x, W_ih, b_ih, b_hh,
                                            blobW, blobTA, blobTB, xproj);
    k2_scan<<<1, 512, 0, stream>>>(hidden0, blobW, blobTA, blobTB, xproj, Hs);
    k3_out<<<STEPS, 128, 0, stream>>>(Hs, W_out, b_out, out);
}